// Round 12
// baseline (153.142 us; speedup 1.0000x reference)
//
#include <hip/hip_runtime.h>
#include <hip/hip_fp16.h>

#define Tt 64
#define Ee 128
#define Aa 10
#define Vv 32001

typedef __attribute__((ext_vector_type(8))) _Float16 half8;
typedef __attribute__((ext_vector_type(4))) _Float16 half4;
typedef __attribute__((ext_vector_type(4))) float f32x4;

#define L2E 1.44269504f

__device__ __forceinline__ float fast_rcp(float x) { return __builtin_amdgcn_rcpf(x); }
__device__ __forceinline__ float fast_exp2(float x) {
#if __has_builtin(__builtin_amdgcn_exp2f)
    return __builtin_amdgcn_exp2f(x);
#else
    return __expf(x * 0.69314718056f);
#endif
}

__device__ __forceinline__ half8 load_h8(const float* p) {
    f32x4 a = *(const f32x4*)p;
    f32x4 b = *(const f32x4*)(p + 4);
    half8 r;
    r[0] = (_Float16)a[0]; r[1] = (_Float16)a[1]; r[2] = (_Float16)a[2]; r[3] = (_Float16)a[3];
    r[4] = (_Float16)b[0]; r[5] = (_Float16)b[1]; r[6] = (_Float16)b[2]; r[7] = (_Float16)b[3];
    return r;
}
__device__ __forceinline__ half8 load_h8s(const float* p, float s) {
    f32x4 a = *(const f32x4*)p;
    f32x4 b = *(const f32x4*)(p + 4);
    half8 r;
#pragma unroll
    for (int j = 0; j < 4; ++j) { r[j] = (_Float16)(a[j] * s); r[4 + j] = (_Float16)(b[j] * s); }
    return r;
}

#define MFMA_F16(a, b, c)  __builtin_amdgcn_mfma_f32_16x16x32_f16(a, b, c, 0, 0, 0)

// lgkm-only barrier: DS traffic drained (cross-wave h exchange); vmem gathers
// stay in flight across the barrier (consumed at next step's C-init).
#define BAR_LGKM() do { \
    asm volatile("s_waitcnt lgkmcnt(0)" ::: "memory"); \
    __builtin_amdgcn_s_barrier(); \
} while (0)

// ============================================================================
// Precompute (folded 3-gate): gi table layout _Float16[v][128][4] = {r',z',n',0}
// r' = -log2e*(emb@wr + bir + bhr), z' likewise, n' = 2log2e*(emb@wn + bin).
// ============================================================================
__global__ __launch_bounds__(512, 2) void gi_precompute(
    const float* __restrict__ emb, const float* __restrict__ w_ih,
    const float* __restrict__ b_ih, const float* __restrict__ b_hh,
    char* __restrict__ gw) {
    __shared__ __align__(16) char xs[8192];  // [32][128] f16 swizzled
    const int tid = threadIdx.x;
    const int wv = tid >> 6;
    const int ln = tid & 63;
    const int fn = ln & 15;
    const int kg = ln >> 4;
    const int v0 = blockIdx.x * 32;
    const int gc = wv * 16 + fn;
    const int srow = tid >> 4;
    const int c8 = (tid & 15) << 3;

    {
        int v = v0 + srow; if (v >= Vv) v = Vv - 1;
        half8 hx = load_h8(emb + (size_t)v * Ee + c8);
        int off = (srow * 256 + c8 * 2) ^ ((srow & 7) << 4);
        *(half8*)(xs + off) = hx;
    }
    half8 wr[4], wz[4], wn[4];
#pragma unroll
    for (int kt = 0; kt < 4; ++kt) {
        int k0 = kt * 32 + kg * 8;
        wr[kt] = load_h8(w_ih + (size_t)gc * Ee + k0);
        wz[kt] = load_h8(w_ih + (size_t)(128 + gc) * Ee + k0);
        wn[kt] = load_h8(w_ih + (size_t)(256 + gc) * Ee + k0);
    }
    const float bcr = b_ih[gc] + b_hh[gc];
    const float bcz = b_ih[128 + gc] + b_hh[128 + gc];
    const float bcn = b_ih[256 + gc];
    __syncthreads();

    f32x4 ar[2], az[2], an[2];
#pragma unroll
    for (int mt = 0; mt < 2; ++mt) {
        ar[mt] = (f32x4){0.f, 0.f, 0.f, 0.f};
        az[mt] = (f32x4){0.f, 0.f, 0.f, 0.f};
        an[mt] = (f32x4){0.f, 0.f, 0.f, 0.f};
    }
#pragma unroll
    for (int kt = 0; kt < 4; ++kt)
#pragma unroll
        for (int mt = 0; mt < 2; ++mt) {
            int r = mt * 16 + fn;
            int off = (r * 256 + (kt * 32 + kg * 8) * 2) ^ ((r & 7) << 4);
            half8 ha = *(const half8*)(xs + off);
            ar[mt] = MFMA_F16(ha, wr[kt], ar[mt]);
            az[mt] = MFMA_F16(ha, wz[kt], az[mt]);
            an[mt] = MFMA_F16(ha, wn[kt], an[mt]);
        }
#pragma unroll
    for (int mt = 0; mt < 2; ++mt)
#pragma unroll
        for (int i = 0; i < 4; ++i) {
            int v = v0 + mt * 16 + kg * 4 + i;
            if (v < Vv) {
                half4 g;
                g[0] = (_Float16)((ar[mt][i] + bcr) * (-L2E));
                g[1] = (_Float16)((az[mt][i] + bcz) * (-L2E));
                g[2] = (_Float16)((an[mt][i] + bcn) * (2.f * L2E));
                g[3] = (_Float16)0.f;
                *(half4*)(gw + (size_t)v * 1024 + gc * 8) = g;
            }
        }
}

// ============================================================================
// Main: 16 rows/block, 8 waves (512 thr), wave owns ONE 16-col tile; 4 elems
// per lane. Grid 512 -> 4096 waves = 16/CU = 4 waves/SIMD: latency hiding via
// wave interleave (2 blocks/CU, independent barrier domains). One lgkm-only
// barrier per step. gi double-buffered in regs via 2-step unroll (no copies).
// LDS (13120 B): tokb [16][64] int(byte-offs) 0..4096 | H0 4096 | H1 8192 |
//                lg 12288..13056 | tstar 13056..13120
//                (epilogue outst f32 [16][128] aliases 4096..12288)
// ============================================================================
#define SM_BYTES 13120

__global__ __launch_bounds__(512, 2) void gru_octo_kernel(
    const int* __restrict__ utt, const char* __restrict__ gwc,
    const float* __restrict__ w_hh, const float* __restrict__ b_hh,
    const float* __restrict__ w_out, const float* __restrict__ b_out,
    float* __restrict__ out) {
    __shared__ __align__(16) char smem[SM_BYTES];
    int* tokb = (int*)smem;
    float* lg = (float*)(smem + 12288);
    int* tstar = (int*)(smem + 13056);
    float* outst = (float*)(smem + 4096);

    const int tid = threadIdx.x;
    const int wv = tid >> 6;      // 0..7
    const int ln = tid & 63;
    const int fn = ln & 15;
    const int kg = ln >> 4;
    const int row0 = blockIdx.x * 16;
    const int gc = wv * 16 + fn;
    const int gc8 = gc * 8;

    // ---- prologue ----
    if (tid < 16) tstar[tid] = Tt - 1;
    *(float2*)(smem + 4096 + tid * 8) = (float2){0.f, 0.f};  // H0 = h(-1) = 0
    __syncthreads();
    {
        // 16 rows * 64 tokens = 1024 ints -> int2 per thread (512 thr)
        int2 tv = ((const int2*)(utt + (size_t)row0 * Tt))[tid];
        int2 sv = {tv.x << 10, tv.y << 10};  // byte offsets into gi table
        ((int2*)tokb)[tid] = sv;
        int row = tid >> 5;
        int tq = (tid & 31) << 1;
        if (tv.x == 0) atomicMin(&tstar[row], tq);
        if (tv.y == 0) atomicMin(&tstar[row], tq + 1);
    }
    half8 whr[4], whz[4], whn[4];
#pragma unroll
    for (int kt = 0; kt < 4; ++kt) {
        int k0 = kt * 32 + kg * 8;
        whr[kt] = load_h8s(w_hh + (size_t)gc * Ee + k0, -L2E);
        whz[kt] = load_h8s(w_hh + (size_t)(128 + gc) * Ee + k0, -L2E);
        whn[kt] = load_h8s(w_hh + (size_t)(256 + gc) * Ee + k0, 2.f * L2E);
    }
    const float bhn2 = b_hh[256 + gc] * (2.f * L2E);
    __syncthreads();   // tokb + tstar ready

    int offk[4], wof[4], toff[4], ts[4];
#pragma unroll
    for (int kt = 0; kt < 4; ++kt)
        offk[kt] = (fn * 256 + (kt * 32 + kg * 8) * 2) ^ ((fn & 7) << 4);
#pragma unroll
    for (int i = 0; i < 4; ++i) {
        int row = kg * 4 + i;
        wof[i] = (row * 256 + gc * 2) ^ ((row & 7) << 4);
        toff[i] = row * 64;
        ts[i] = tstar[row];
    }

    // gi(0) into gA
    half4 gA[4], gB[4];
#pragma unroll
    for (int i = 0; i < 4; ++i)
        gA[i] = *(const half4*)(gwc + tokb[toff[i]] + gc8);

    f32x4 h = (f32x4){0.f, 0.f, 0.f, 0.f};
    f32x4 o = h;

    // one GRU step: read h(k-1) from RD, gi(k) in GCUR; gather gi(k+1)->GNXT;
    // write h(k) to WR. Barrier applied by caller.
#define STEP(K, RD, WR, GCUR, GNXT) do {                                      \
        half8 f0 = *(const half8*)((RD) + offk[0]);                           \
        half8 f1 = *(const half8*)((RD) + offk[1]);                           \
        half8 f2 = *(const half8*)((RD) + offk[2]);                           \
        half8 f3 = *(const half8*)((RD) + offk[3]);                           \
        int t2 = (K) + 1; if (t2 > Tt - 1) t2 = Tt - 1;                       \
        GNXT[0] = *(const half4*)(gwc + tokb[toff[0] + t2] + gc8);            \
        GNXT[1] = *(const half4*)(gwc + tokb[toff[1] + t2] + gc8);            \
        GNXT[2] = *(const half4*)(gwc + tokb[toff[2] + t2] + gc8);            \
        GNXT[3] = *(const half4*)(gwc + tokb[toff[3] + t2] + gc8);            \
        f32x4 ar, az, an;                                                     \
        _Pragma("unroll")                                                     \
        for (int i = 0; i < 4; ++i) {                                         \
            ar[i] = (float)GCUR[i][0]; az[i] = (float)GCUR[i][1];             \
            an[i] = bhn2;                                                     \
        }                                                                     \
        __builtin_amdgcn_s_setprio(1);                                        \
        ar = MFMA_F16(f0, whr[0], ar); az = MFMA_F16(f0, whz[0], az);         \
        an = MFMA_F16(f0, whn[0], an);                                        \
        ar = MFMA_F16(f1, whr[1], ar); az = MFMA_F16(f1, whz[1], az);         \
        an = MFMA_F16(f1, whn[1], an);                                        \
        ar = MFMA_F16(f2, whr[2], ar); az = MFMA_F16(f2, whz[2], az);         \
        an = MFMA_F16(f2, whn[2], an);                                        \
        ar = MFMA_F16(f3, whr[3], ar); az = MFMA_F16(f3, whz[3], az);         \
        an = MFMA_F16(f3, whn[3], an);                                        \
        __builtin_amdgcn_s_setprio(0);                                        \
        bool wr_ = (K) < Tt - 1;                                              \
        _Pragma("unroll")                                                     \
        for (int i = 0; i < 4; ++i) {                                         \
            float ea = fast_exp2(ar[i]);                                      \
            float eb = fast_exp2(az[i]);                                      \
            float da = 1.f + ea, db = 1.f + eb;                               \
            float R = fast_rcp(da * db);                                      \
            float rr = db * R, zz = da * R;                                   \
            float pnp = (float)GCUR[i][2] + rr * an[i];                       \
            float ec = fast_exp2(pnp);                                        \
            float nn = 1.f - 2.f * fast_rcp(ec + 1.f);                        \
            float hv = nn + zz * (h[i] - nn);                                 \
            h[i] = hv;                                                        \
            if ((K) == ts[i]) o[i] = hv;                                      \
            if (wr_) *(_Float16*)((WR) + wof[i]) = (_Float16)hv;              \
        }                                                                     \
    } while (0)

#pragma unroll 1
    for (int k = 0; k < Tt; k += 2) {
        STEP(k, smem + 4096, smem + 8192, gA, gB);
        BAR_LGKM();  // h(k) visible; gi gathers stay in flight
        STEP(k + 1, smem + 8192, smem + 4096, gB, gA);
        BAR_LGKM();
    }
#undef STEP

    // ---- epilogue: logits + softmax (outst aliases H; last barrier drained) ----
#pragma unroll
    for (int i = 0; i < 4; ++i) outst[(kg * 4 + i) * Ee + gc] = o[i];
    __syncthreads();

    if (tid < 16 * Aa) {
        int r = tid / Aa, a = tid % Aa;
        const float* wo = w_out + a * Ee;
        const float* os = outst + r * Ee;
        float s = b_out[a];
#pragma unroll
        for (int j = 0; j < Ee; j += 4) {
            f32x4 ov = *(const f32x4*)(os + j);
            f32x4 w4 = *(const f32x4*)(wo + j);
            s += ov[0] * w4[0] + ov[1] * w4[1] + ov[2] * w4[2] + ov[3] * w4[3];
        }
        lg[r * 12 + a] = s;
    }
    __syncthreads();
    if (tid < 16) {
        float v[Aa];
        float mx = -1e30f;
#pragma unroll
        for (int a = 0; a < Aa; ++a) {
            v[a] = lg[tid * 12 + a];
            mx = fmaxf(mx, v[a]);
        }
        float sum = 0.f;
#pragma unroll
        for (int a = 0; a < Aa; ++a) {
            v[a] = __expf(v[a] - mx);
            sum += v[a];
        }
        float inv = fast_rcp(sum);
#pragma unroll
        for (int a = 0; a < Aa; ++a) out[(size_t)(row0 + tid) * Aa + a] = v[a] * inv;
    }
}

// ============================================================================
// Fallback (R5 kernel) if ws can't hold the gi table.
// ============================================================================
#define FSM_BYTES 21312
__global__ __launch_bounds__(512, 2) void gru_fallback_kernel(
    const int* __restrict__ utt, const float* __restrict__ emb,
    const float* __restrict__ w_ih, const float* __restrict__ w_hh,
    const float* __restrict__ b_ih, const float* __restrict__ b_hh,
    const float* __restrict__ w_out, const float* __restrict__ b_out,
    float* __restrict__ out) {
    __shared__ __align__(16) char smem[FSM_BYTES];
    int* tokb = (int*)smem;
    float* lg = (float*)(smem + 20480);
    int* tstar = (int*)(smem + 21248);
    float* outst = (float*)(smem + 4096);

    const int tid = threadIdx.x;
    const int wv = tid >> 6;
    const int ln = tid & 63;
    const int fn = ln & 15;
    const int kg = ln >> 4;
    const int row0 = blockIdx.x * 16;
    const int gc = wv * 16 + fn;
    const int srow = tid >> 5;
    const int c4 = (tid & 31) << 2;

    if (tid < 16) tstar[tid] = Tt - 1;
    *(float2*)(smem + 12288 + tid * 8) = (float2){0.f, 0.f};
    __syncthreads();
    {
        int2 tv = ((const int2*)(utt + (size_t)row0 * Tt))[tid];
        ((int2*)tokb)[tid] = tv;
        int row = tid >> 5;
        int tq = (tid & 31) << 1;
        if (tv.x == 0) atomicMin(&tstar[row], tq);
        if (tv.y == 0) atomicMin(&tstar[row], tq + 1);
    }
    half8 wir[4], wiz[4], win[4], whr[4], whz[4], whn[4];
#pragma unroll
    for (int kt = 0; kt < 4; ++kt) {
        int k0 = kt * 32 + kg * 8;
        wir[kt] = load_h8(w_ih + (size_t)gc * Ee + k0);
        wiz[kt] = load_h8(w_ih + (size_t)(128 + gc) * Ee + k0);
        win[kt] = load_h8(w_ih + (size_t)(256 + gc) * Ee + k0);
        whr[kt] = load_h8(w_hh + (size_t)gc * Ee + k0);
        whz[kt] = load_h8(w_hh + (size_t)(128 + gc) * Ee + k0);
        whn[kt] = load_h8(w_hh + (size_t)(256 + gc) * Ee + k0);
    }
    const float bcr = b_ih[gc] + b_hh[gc];
    const float bcz = b_ih[128 + gc] + b_hh[128 + gc];
    const float bin = b_ih[256 + gc];
    const float bhn = b_hh[256 + gc];
    __syncthreads();
    int ts[4];
#pragma unroll
    for (int i = 0; i < 4; ++i) ts[i] = tstar[kg * 4 + i];
    {
        int tok = tokb[srow * Tt];
        f32x4 a = *(const f32x4*)(emb + (size_t)tok * Ee + c4);
        half4 hx;
#pragma unroll
        for (int j = 0; j < 4; ++j) hx[j] = (_Float16)a[j];
        int off = (srow * 256 + c4 * 2) ^ ((srow & 7) << 4);
        *(half4*)(smem + 4096 + off) = hx;
    }
    __syncthreads();
    f32x4 hreg = (f32x4){0.f, 0.f, 0.f, 0.f};
    f32x4 oreg = (f32x4){0.f, 0.f, 0.f, 0.f};
    int cur = 0;
#pragma unroll 1
    for (int t = 0; t < Tt; ++t) {
        f32x4 pa;
        if (t < Tt - 1) {
            int tok = tokb[srow * Tt + t + 1];
            pa = *(const f32x4*)(emb + (size_t)tok * Ee + c4);
        }
        const char* xb = smem + 4096 + cur * 4096;
        const char* hb = smem + 12288 + cur * 4096;
        f32x4 ar = (f32x4){0.f, 0.f, 0.f, 0.f};
        f32x4 az = (f32x4){0.f, 0.f, 0.f, 0.f};
        f32x4 ain = (f32x4){0.f, 0.f, 0.f, 0.f};
        f32x4 ahn = (f32x4){0.f, 0.f, 0.f, 0.f};
        __builtin_amdgcn_s_setprio(1);
#pragma unroll
        for (int kt = 0; kt < 4; ++kt) {
            int off = (fn * 256 + (kt * 32 + kg * 8) * 2) ^ ((fn & 7) << 4);
            half8 xa = *(const half8*)(xb + off);
            half8 ha = *(const half8*)(hb + off);
            ar = MFMA_F16(xa, wir[kt], ar);
            ar = MFMA_F16(ha, whr[kt], ar);
            az = MFMA_F16(xa, wiz[kt], az);
            az = MFMA_F16(ha, whz[kt], az);
            ain = MFMA_F16(xa, win[kt], ain);
            ahn = MFMA_F16(ha, whn[kt], ahn);
        }
        __builtin_amdgcn_s_setprio(0);
        char* hn = smem + 12288 + (cur ^ 1) * 4096;
#pragma unroll
        for (int i = 0; i < 4; ++i) {
            float pr = ar[i] + bcr;
            float pz = az[i] + bcz;
            float rr = fast_rcp(1.f + __expf(-pr));
            float zz = fast_rcp(1.f + __expf(-pz));
            float pn = ain[i] + bin + rr * (ahn[i] + bhn);
            float e2 = __expf(2.f * pn);
            float nn = 1.f - 2.f * fast_rcp(e2 + 1.f);
            float h = (1.f - zz) * nn + zz * hreg[i];
            hreg[i] = h;
            if (t == ts[i]) oreg[i] = h;
            if (t < Tt - 1) {
                int row = kg * 4 + i;
                int off = (row * 256 + gc * 2) ^ ((row & 7) << 4);
                *(_Float16*)(hn + off) = (_Float16)h;
            }
        }
        if (t < Tt - 1) {
            half4 hx;
#pragma unroll
            for (int j = 0; j < 4; ++j) hx[j] = (_Float16)pa[j];
            int off = (srow * 256 + c4 * 2) ^ ((srow & 7) << 4);
            *(half4*)(smem + 4096 + (cur ^ 1) * 4096 + off) = hx;
        }
        __syncthreads();
        cur ^= 1;
    }
#pragma unroll
    for (int i = 0; i < 4; ++i) outst[(kg * 4 + i) * Ee + gc] = oreg[i];
    __syncthreads();
    if (tid < 16 * Aa) {
        int r = tid / Aa, a = tid % Aa;
        const float* wo = w_out + a * Ee;
        const float* os = outst + r * Ee;
        float s = b_out[a];
#pragma unroll
        for (int j = 0; j < Ee; j += 4) {
            f32x4 o = *(const f32x4*)(os + j);
            f32x4 w4 = *(const f32x4*)(wo + j);
            s += o[0] * w4[0] + o[1] * w4[1] + o[2] * w4[2] + o[3] * w4[3];
        }
        lg[r * 12 + a] = s;
    }
    __syncthreads();
    if (tid < 16) {
        float v[Aa];
        float mx = -1e30f;
#pragma unroll
        for (int a = 0; a < Aa; ++a) {
            v[a] = lg[tid * 12 + a];
            mx = fmaxf(mx, v[a]);
        }
        float sum = 0.f;
#pragma unroll
        for (int a = 0; a < Aa; ++a) {
            v[a] = __expf(v[a] - mx);
            sum += v[a];
        }
        float inv = fast_rcp(sum);
#pragma unroll
        for (int a = 0; a < Aa; ++a) out[(size_t)(row0 + tid) * Aa + a] = v[a] * inv;
    }
}

extern "C" void kernel_launch(void* const* d_in, const int* in_sizes, int n_in,
                              void* d_out, int out_size, void* d_ws, size_t ws_size,
                              hipStream_t stream) {
    (void)in_sizes; (void)n_in; (void)out_size;
    const int* utt = (const int*)d_in[0];
    const float* emb = (const float*)d_in[2];
    const float* wih = (const float*)d_in[3];
    const float* whh = (const float*)d_in[4];
    const float* bih = (const float*)d_in[5];
    const float* bhh = (const float*)d_in[6];
    const float* wout = (const float*)d_in[7];
    const float* bout = (const float*)d_in[8];
    const size_t need = (size_t)Vv * 1024;  // 32.77 MB
    if (ws_size >= need) {
        char* gw = (char*)d_ws;
        gi_precompute<<<dim3((Vv + 31) / 32), 512, 0, stream>>>(emb, wih, bih, bhh, gw);
        gru_octo_kernel<<<512, 512, 0, stream>>>(utt, gw, whh, bhh, wout, bout, (float*)d_out);
    } else {
        gru_fallback_kernel<<<512, 512, 0, stream>>>(utt, emb, wih, whh, bih, bhh, wout, bout,
                                                     (float*)d_out);
    }
}

// Round 13
// 125.540 us; speedup vs baseline: 1.2199x; 1.2199x over previous
//
#include <hip/hip_runtime.h>
#include <hip/hip_fp16.h>

#define Tt 64
#define Ee 128
#define Aa 10
#define Vv 32001

typedef __attribute__((ext_vector_type(8))) _Float16 half8;
typedef __attribute__((ext_vector_type(4))) _Float16 half4;
typedef __attribute__((ext_vector_type(4))) float f32x4;

#define L2E 1.44269504f

__device__ __forceinline__ float fast_rcp(float x) { return __builtin_amdgcn_rcpf(x); }
__device__ __forceinline__ float fast_exp2(float x) {
#if __has_builtin(__builtin_amdgcn_exp2f)
    return __builtin_amdgcn_exp2f(x);
#else
    return __expf(x * 0.69314718056f);
#endif
}

__device__ __forceinline__ half8 load_h8(const float* p) {
    f32x4 a = *(const f32x4*)p;
    f32x4 b = *(const f32x4*)(p + 4);
    half8 r;
    r[0] = (_Float16)a[0]; r[1] = (_Float16)a[1]; r[2] = (_Float16)a[2]; r[3] = (_Float16)a[3];
    r[4] = (_Float16)b[0]; r[5] = (_Float16)b[1]; r[6] = (_Float16)b[2]; r[7] = (_Float16)b[3];
    return r;
}
__device__ __forceinline__ half8 load_h8s(const float* p, float s) {
    f32x4 a = *(const f32x4*)p;
    f32x4 b = *(const f32x4*)(p + 4);
    half8 r;
#pragma unroll
    for (int j = 0; j < 4; ++j) { r[j] = (_Float16)(a[j] * s); r[4 + j] = (_Float16)(b[j] * s); }
    return r;
}

#define MFMA_F16(a, b, c)  __builtin_amdgcn_mfma_f32_16x16x32_f16(a, b, c, 0, 0, 0)

// lgkm-only barrier: DS traffic drained (cross-wave h exchange); vmem gathers
// stay in flight across the barrier.
#define BAR_LGKM() do { \
    asm volatile("s_waitcnt lgkmcnt(0)" ::: "memory"); \
    __builtin_amdgcn_s_barrier(); \
} while (0)

// ============================================================================
// Precompute (folded 3-gate): gi table layout _Float16[v][128][4] = {r',z',n',0}
// r' = -log2e*(emb@wr + bir + bhr), z' likewise, n' = 2log2e*(emb@wn + bin).
// ============================================================================
__global__ __launch_bounds__(512, 2) void gi_precompute(
    const float* __restrict__ emb, const float* __restrict__ w_ih,
    const float* __restrict__ b_ih, const float* __restrict__ b_hh,
    char* __restrict__ gw) {
    __shared__ __align__(16) char xs[8192];  // [32][128] f16 swizzled
    const int tid = threadIdx.x;
    const int wv = tid >> 6;
    const int ln = tid & 63;
    const int fn = ln & 15;
    const int kg = ln >> 4;
    const int v0 = blockIdx.x * 32;
    const int gc = wv * 16 + fn;
    const int srow = tid >> 4;
    const int c8 = (tid & 15) << 3;

    {
        int v = v0 + srow; if (v >= Vv) v = Vv - 1;
        half8 hx = load_h8(emb + (size_t)v * Ee + c8);
        int off = (srow * 256 + c8 * 2) ^ ((srow & 7) << 4);
        *(half8*)(xs + off) = hx;
    }
    half8 wr[4], wz[4], wn[4];
#pragma unroll
    for (int kt = 0; kt < 4; ++kt) {
        int k0 = kt * 32 + kg * 8;
        wr[kt] = load_h8(w_ih + (size_t)gc * Ee + k0);
        wz[kt] = load_h8(w_ih + (size_t)(128 + gc) * Ee + k0);
        wn[kt] = load_h8(w_ih + (size_t)(256 + gc) * Ee + k0);
    }
    const float bcr = b_ih[gc] + b_hh[gc];
    const float bcz = b_ih[128 + gc] + b_hh[128 + gc];
    const float bcn = b_ih[256 + gc];
    __syncthreads();

    f32x4 ar[2], az[2], an[2];
#pragma unroll
    for (int mt = 0; mt < 2; ++mt) {
        ar[mt] = (f32x4){0.f, 0.f, 0.f, 0.f};
        az[mt] = (f32x4){0.f, 0.f, 0.f, 0.f};
        an[mt] = (f32x4){0.f, 0.f, 0.f, 0.f};
    }
#pragma unroll
    for (int kt = 0; kt < 4; ++kt)
#pragma unroll
        for (int mt = 0; mt < 2; ++mt) {
            int r = mt * 16 + fn;
            int off = (r * 256 + (kt * 32 + kg * 8) * 2) ^ ((r & 7) << 4);
            half8 ha = *(const half8*)(xs + off);
            ar[mt] = MFMA_F16(ha, wr[kt], ar[mt]);
            az[mt] = MFMA_F16(ha, wz[kt], az[mt]);
            an[mt] = MFMA_F16(ha, wn[kt], an[mt]);
        }
#pragma unroll
    for (int mt = 0; mt < 2; ++mt)
#pragma unroll
        for (int i = 0; i < 4; ++i) {
            int v = v0 + mt * 16 + kg * 4 + i;
            if (v < Vv) {
                half4 g;
                g[0] = (_Float16)((ar[mt][i] + bcr) * (-L2E));
                g[1] = (_Float16)((az[mt][i] + bcz) * (-L2E));
                g[2] = (_Float16)((an[mt][i] + bcn) * (2.f * L2E));
                g[3] = (_Float16)0.f;
                *(half4*)(gw + (size_t)v * 1024 + gc * 8) = g;
            }
        }
}

// ============================================================================
// Main: 16 rows/block, 8 waves (512 thr), wave owns ONE 16-col tile; 4 elems
// per lane. Slimmed to VGPR<=64 (launch_bounds(512,4) caps at 64; R4/R6
// precedent: VGPR<=64 is the boundary for 2 co-resident 8-wave blocks/CU).
// Single gi reg buffer (extract-then-overwrite), o snapshot in LDS, toff
// folded into addressing. One lgkm-only barrier per step.
// LDS (21312 B): tokb [16][64] int(byte-offs) 0..4096 | H0 4096 | H1 8192 |
//                ost [16][128] f32 12288..20480 | lg 20480..21248 |
//                tstar 21248..21312
// ============================================================================
#define SM_BYTES 21312

__global__ __launch_bounds__(512, 4) void gru_slim_kernel(
    const int* __restrict__ utt, const char* __restrict__ gwc,
    const float* __restrict__ w_hh, const float* __restrict__ b_hh,
    const float* __restrict__ w_out, const float* __restrict__ b_out,
    float* __restrict__ out) {
    __shared__ __align__(16) char smem[SM_BYTES];
    int* tokb = (int*)smem;
    float* ost = (float*)(smem + 12288);
    float* lg = (float*)(smem + 20480);
    int* tstar = (int*)(smem + 21248);

    const int tid = threadIdx.x;
    const int wv = tid >> 6;      // 0..7
    const int ln = tid & 63;
    const int fn = ln & 15;
    const int kg = ln >> 4;
    const int row0 = blockIdx.x * 16;
    const int gc = wv * 16 + fn;
    const int gc8 = gc * 8;

    // ---- prologue ----
    if (tid < 16) tstar[tid] = Tt - 1;
    *(float2*)(smem + 4096 + tid * 8) = (float2){0.f, 0.f};  // H0 = h(-1) = 0
    __syncthreads();
    {
        // 16 rows * 64 tokens = 1024 ints -> int2 per thread (512 thr)
        int2 tv = ((const int2*)(utt + (size_t)row0 * Tt))[tid];
        int2 sv = {tv.x << 10, tv.y << 10};  // byte offsets into gi table
        ((int2*)tokb)[tid] = sv;
        int row = tid >> 5;
        int tq = (tid & 31) << 1;
        if (tv.x == 0) atomicMin(&tstar[row], tq);
        if (tv.y == 0) atomicMin(&tstar[row], tq + 1);
    }
    half8 whr[4], whz[4], whn[4];
#pragma unroll
    for (int kt = 0; kt < 4; ++kt) {
        int k0 = kt * 32 + kg * 8;
        whr[kt] = load_h8s(w_hh + (size_t)gc * Ee + k0, -L2E);
        whz[kt] = load_h8s(w_hh + (size_t)(128 + gc) * Ee + k0, -L2E);
        whn[kt] = load_h8s(w_hh + (size_t)(256 + gc) * Ee + k0, 2.f * L2E);
    }
    const float bhn2 = b_hh[256 + gc] * (2.f * L2E);
    __syncthreads();   // tokb + tstar ready

    int offk[4], wof[4], ts[4];
#pragma unroll
    for (int kt = 0; kt < 4; ++kt)
        offk[kt] = (fn * 256 + (kt * 32 + kg * 8) * 2) ^ ((fn & 7) << 4);
#pragma unroll
    for (int i = 0; i < 4; ++i) {
        int row = kg * 4 + i;
        wof[i] = (row * 256 + gc * 2) ^ ((row & 7) << 4);
        ts[i] = tstar[row];
    }
    const int tokbase = kg * 256;  // tokb[tokbase + i*64 + t]

    // gi(0) into g (single buffer)
    half4 g[4];
#pragma unroll
    for (int i = 0; i < 4; ++i)
        g[i] = *(const half4*)(gwc + tokb[tokbase + i * 64] + gc8);

    f32x4 h = (f32x4){0.f, 0.f, 0.f, 0.f};

#pragma unroll 1
    for (int k = 0; k < Tt; ++k) {
        const char* RD = smem + 4096 + ((k & 1) << 12);
        char* WR = smem + 4096 + (((k + 1) & 1) << 12);
        // ---- h-frag reads (h(k-1)) ----
        half8 f0 = *(const half8*)(RD + offk[0]);
        half8 f1 = *(const half8*)(RD + offk[1]);
        half8 f2 = *(const half8*)(RD + offk[2]);
        half8 f3 = *(const half8*)(RD + offk[3]);
        // ---- extract gi(k) (r,z -> C-init; n -> pnh), then re-gather into g ----
        f32x4 ar, az, an;
        half4 pnh;
#pragma unroll
        for (int i = 0; i < 4; ++i) {
            ar[i] = (float)g[i][0];
            az[i] = (float)g[i][1];
            an[i] = bhn2;
            pnh[i] = g[i][2];
        }
        int t2 = k + 1; if (t2 > Tt - 1) t2 = Tt - 1;
        g[0] = *(const half4*)(gwc + tokb[tokbase + t2] + gc8);
        g[1] = *(const half4*)(gwc + tokb[tokbase + 64 + t2] + gc8);
        g[2] = *(const half4*)(gwc + tokb[tokbase + 128 + t2] + gc8);
        g[3] = *(const half4*)(gwc + tokb[tokbase + 192 + t2] + gc8);
        // ---- MFMA ----
        __builtin_amdgcn_s_setprio(1);
        ar = MFMA_F16(f0, whr[0], ar); az = MFMA_F16(f0, whz[0], az);
        an = MFMA_F16(f0, whn[0], an);
        ar = MFMA_F16(f1, whr[1], ar); az = MFMA_F16(f1, whz[1], az);
        an = MFMA_F16(f1, whn[1], an);
        ar = MFMA_F16(f2, whr[2], ar); az = MFMA_F16(f2, whz[2], az);
        an = MFMA_F16(f2, whn[2], an);
        ar = MFMA_F16(f3, whr[3], ar); az = MFMA_F16(f3, whz[3], az);
        an = MFMA_F16(f3, whn[3], an);
        __builtin_amdgcn_s_setprio(0);
        // ---- gates; h(k) to next buffer; snapshot to ost at death step ----
        bool wr_ = (k < Tt - 1);
#pragma unroll
        for (int i = 0; i < 4; ++i) {
            float ea = fast_exp2(ar[i]);
            float eb = fast_exp2(az[i]);
            float da = 1.f + ea, db = 1.f + eb;
            float R = fast_rcp(da * db);
            float rr = db * R, zz = da * R;
            float pnp = (float)pnh[i] + rr * an[i];
            float ec = fast_exp2(pnp);
            float nn = 1.f - 2.f * fast_rcp(ec + 1.f);
            float hv = nn + zz * (h[i] - nn);
            h[i] = hv;
            if (k == ts[i]) ost[(kg * 4 + i) * Ee + gc] = hv;
            if (wr_) *(_Float16*)(WR + wof[i]) = (_Float16)hv;
        }
        BAR_LGKM();  // h(k) + ost writes visible; gi gathers stay in flight
    }

    // ---- epilogue: logits + softmax from ost ----
    __syncthreads();
    if (tid < 16 * Aa) {
        int r = tid / Aa, a = tid % Aa;
        const float* wo = w_out + a * Ee;
        const float* os = ost + r * Ee;
        float s = b_out[a];
#pragma unroll
        for (int j = 0; j < Ee; j += 4) {
            f32x4 ov = *(const f32x4*)(os + j);
            f32x4 w4 = *(const f32x4*)(wo + j);
            s += ov[0] * w4[0] + ov[1] * w4[1] + ov[2] * w4[2] + ov[3] * w4[3];
        }
        lg[r * 12 + a] = s;
    }
    __syncthreads();
    if (tid < 16) {
        float v[Aa];
        float mx = -1e30f;
#pragma unroll
        for (int a = 0; a < Aa; ++a) {
            v[a] = lg[tid * 12 + a];
            mx = fmaxf(mx, v[a]);
        }
        float sum = 0.f;
#pragma unroll
        for (int a = 0; a < Aa; ++a) {
            v[a] = __expf(v[a] - mx);
            sum += v[a];
        }
        float inv = fast_rcp(sum);
#pragma unroll
        for (int a = 0; a < Aa; ++a) out[(size_t)(row0 + tid) * Aa + a] = v[a] * inv;
    }
}

// ============================================================================
// Fallback (R5 kernel) if ws can't hold the gi table.
// ============================================================================
#define FSM_BYTES 21312
__global__ __launch_bounds__(512, 2) void gru_fallback_kernel(
    const int* __restrict__ utt, const float* __restrict__ emb,
    const float* __restrict__ w_ih, const float* __restrict__ w_hh,
    const float* __restrict__ b_ih, const float* __restrict__ b_hh,
    const float* __restrict__ w_out, const float* __restrict__ b_out,
    float* __restrict__ out) {
    __shared__ __align__(16) char smem[FSM_BYTES];
    int* tokb = (int*)smem;
    float* lg = (float*)(smem + 20480);
    int* tstar = (int*)(smem + 21248);
    float* outst = (float*)(smem + 4096);

    const int tid = threadIdx.x;
    const int wv = tid >> 6;
    const int ln = tid & 63;
    const int fn = ln & 15;
    const int kg = ln >> 4;
    const int row0 = blockIdx.x * 16;
    const int gc = wv * 16 + fn;
    const int srow = tid >> 5;
    const int c4 = (tid & 31) << 2;

    if (tid < 16) tstar[tid] = Tt - 1;
    *(float2*)(smem + 12288 + tid * 8) = (float2){0.f, 0.f};
    __syncthreads();
    {
        int2 tv = ((const int2*)(utt + (size_t)row0 * Tt))[tid];
        ((int2*)tokb)[tid] = tv;
        int row = tid >> 5;
        int tq = (tid & 31) << 1;
        if (tv.x == 0) atomicMin(&tstar[row], tq);
        if (tv.y == 0) atomicMin(&tstar[row], tq + 1);
    }
    half8 wir[4], wiz[4], win[4], whr[4], whz[4], whn[4];
#pragma unroll
    for (int kt = 0; kt < 4; ++kt) {
        int k0 = kt * 32 + kg * 8;
        wir[kt] = load_h8(w_ih + (size_t)gc * Ee + k0);
        wiz[kt] = load_h8(w_ih + (size_t)(128 + gc) * Ee + k0);
        win[kt] = load_h8(w_ih + (size_t)(256 + gc) * Ee + k0);
        whr[kt] = load_h8(w_hh + (size_t)gc * Ee + k0);
        whz[kt] = load_h8(w_hh + (size_t)(128 + gc) * Ee + k0);
        whn[kt] = load_h8(w_hh + (size_t)(256 + gc) * Ee + k0);
    }
    const float bcr = b_ih[gc] + b_hh[gc];
    const float bcz = b_ih[128 + gc] + b_hh[128 + gc];
    const float bin = b_ih[256 + gc];
    const float bhn = b_hh[256 + gc];
    __syncthreads();
    int ts[4];
#pragma unroll
    for (int i = 0; i < 4; ++i) ts[i] = tstar[kg * 4 + i];
    {
        int tok = tokb[srow * Tt];
        f32x4 a = *(const f32x4*)(emb + (size_t)tok * Ee + c4);
        half4 hx;
#pragma unroll
        for (int j = 0; j < 4; ++j) hx[j] = (_Float16)a[j];
        int off = (srow * 256 + c4 * 2) ^ ((srow & 7) << 4);
        *(half4*)(smem + 4096 + off) = hx;
    }
    __syncthreads();
    f32x4 hreg = (f32x4){0.f, 0.f, 0.f, 0.f};
    f32x4 oreg = (f32x4){0.f, 0.f, 0.f, 0.f};
    int cur = 0;
#pragma unroll 1
    for (int t = 0; t < Tt; ++t) {
        f32x4 pa;
        if (t < Tt - 1) {
            int tok = tokb[srow * Tt + t + 1];
            pa = *(const f32x4*)(emb + (size_t)tok * Ee + c4);
        }
        const char* xb = smem + 4096 + cur * 4096;
        const char* hb = smem + 12288 + cur * 4096;
        f32x4 ar = (f32x4){0.f, 0.f, 0.f, 0.f};
        f32x4 az = (f32x4){0.f, 0.f, 0.f, 0.f};
        f32x4 ain = (f32x4){0.f, 0.f, 0.f, 0.f};
        f32x4 ahn = (f32x4){0.f, 0.f, 0.f, 0.f};
        __builtin_amdgcn_s_setprio(1);
#pragma unroll
        for (int kt = 0; kt < 4; ++kt) {
            int off = (fn * 256 + (kt * 32 + kg * 8) * 2) ^ ((fn & 7) << 4);
            half8 xa = *(const half8*)(xb + off);
            half8 ha = *(const half8*)(hb + off);
            ar = MFMA_F16(xa, wir[kt], ar);
            ar = MFMA_F16(ha, whr[kt], ar);
            az = MFMA_F16(xa, wiz[kt], az);
            az = MFMA_F16(ha, whz[kt], az);
            ain = MFMA_F16(xa, win[kt], ain);
            ahn = MFMA_F16(ha, whn[kt], ahn);
        }
        __builtin_amdgcn_s_setprio(0);
        char* hn = smem + 12288 + (cur ^ 1) * 4096;
#pragma unroll
        for (int i = 0; i < 4; ++i) {
            float pr = ar[i] + bcr;
            float pz = az[i] + bcz;
            float rr = fast_rcp(1.f + __expf(-pr));
            float zz = fast_rcp(1.f + __expf(-pz));
            float pn = ain[i] + bin + rr * (ahn[i] + bhn);
            float e2 = __expf(2.f * pn);
            float nn = 1.f - 2.f * fast_rcp(e2 + 1.f);
            float h = (1.f - zz) * nn + zz * hreg[i];
            hreg[i] = h;
            if (t == ts[i]) oreg[i] = h;
            if (t < Tt - 1) {
                int row = kg * 4 + i;
                int off = (row * 256 + gc * 2) ^ ((row & 7) << 4);
                *(_Float16*)(hn + off) = (_Float16)h;
            }
        }
        if (t < Tt - 1) {
            half4 hx;
#pragma unroll
            for (int j = 0; j < 4; ++j) hx[j] = (_Float16)pa[j];
            int off = (srow * 256 + c4 * 2) ^ ((srow & 7) << 4);
            *(half4*)(smem + 4096 + (cur ^ 1) * 4096 + off) = hx;
        }
        __syncthreads();
        cur ^= 1;
    }
#pragma unroll
    for (int i = 0; i < 4; ++i) outst[(kg * 4 + i) * Ee + gc] = oreg[i];
    __syncthreads();
    if (tid < 16 * Aa) {
        int r = tid / Aa, a = tid % Aa;
        const float* wo = w_out + a * Ee;
        const float* os = outst + r * Ee;
        float s = b_out[a];
#pragma unroll
        for (int j = 0; j < Ee; j += 4) {
            f32x4 o = *(const f32x4*)(os + j);
            f32x4 w4 = *(const f32x4*)(wo + j);
            s += o[0] * w4[0] + o[1] * w4[1] + o[2] * w4[2] + o[3] * w4[3];
        }
        lg[r * 12 + a] = s;
    }
    __syncthreads();
    if (tid < 16) {
        float v[Aa];
        float mx = -1e30f;
#pragma unroll
        for (int a = 0; a < Aa; ++a) {
            v[a] = lg[tid * 12 + a];
            mx = fmaxf(mx, v[a]);
        }
        float sum = 0.f;
#pragma unroll
        for (int a = 0; a < Aa; ++a) {
            v[a] = __expf(v[a] - mx);
            sum += v[a];
        }
        float inv = fast_rcp(sum);
#pragma unroll
        for (int a = 0; a < Aa; ++a) out[(size_t)(row0 + tid) * Aa + a] = v[a] * inv;
    }
}

extern "C" void kernel_launch(void* const* d_in, const int* in_sizes, int n_in,
                              void* d_out, int out_size, void* d_ws, size_t ws_size,
                              hipStream_t stream) {
    (void)in_sizes; (void)n_in; (void)out_size;
    const int* utt = (const int*)d_in[0];
    const float* emb = (const float*)d_in[2];
    const float* wih = (const float*)d_in[3];
    const float* whh = (const float*)d_in[4];
    const float* bih = (const float*)d_in[5];
    const float* bhh = (const float*)d_in[6];
    const float* wout = (const float*)d_in[7];
    const float* bout = (const float*)d_in[8];
    const size_t need = (size_t)Vv * 1024;  // 32.77 MB
    if (ws_size >= need) {
        char* gw = (char*)d_ws;
        gi_precompute<<<dim3((Vv + 31) / 32), 512, 0, stream>>>(emb, wih, bih, bhh, gw);
        gru_slim_kernel<<<512, 512, 0, stream>>>(utt, gw, whh, bhh, wout, bout, (float*)d_out);
    } else {
        gru_fallback_kernel<<<512, 512, 0, stream>>>(utt, emb, wih, whh, bih, bhh, wout, bout,
                                                     (float*)d_out);
    }
}

// Round 14
// 120.395 us; speedup vs baseline: 1.2720x; 1.0427x over previous
//
#include <hip/hip_runtime.h>
#include <hip/hip_fp16.h>

#define Tt 64
#define Ee 128
#define Aa 10
#define Vv 32001

typedef __attribute__((ext_vector_type(8))) _Float16 half8;
typedef __attribute__((ext_vector_type(4))) _Float16 half4;
typedef __attribute__((ext_vector_type(4))) float f32x4;

#define L2E 1.44269504f

__device__ __forceinline__ float fast_rcp(float x) { return __builtin_amdgcn_rcpf(x); }
__device__ __forceinline__ float fast_exp2(float x) {
#if __has_builtin(__builtin_amdgcn_exp2f)
    return __builtin_amdgcn_exp2f(x);
#else
    return __expf(x * 0.69314718056f);
#endif
}

__device__ __forceinline__ half8 load_h8(const float* p) {
    f32x4 a = *(const f32x4*)p;
    f32x4 b = *(const f32x4*)(p + 4);
    half8 r;
    r[0] = (_Float16)a[0]; r[1] = (_Float16)a[1]; r[2] = (_Float16)a[2]; r[3] = (_Float16)a[3];
    r[4] = (_Float16)b[0]; r[5] = (_Float16)b[1]; r[6] = (_Float16)b[2]; r[7] = (_Float16)b[3];
    return r;
}
__device__ __forceinline__ half8 load_h8s(const float* p, float s) {
    f32x4 a = *(const f32x4*)p;
    f32x4 b = *(const f32x4*)(p + 4);
    half8 r;
#pragma unroll
    for (int j = 0; j < 4; ++j) { r[j] = (_Float16)(a[j] * s); r[4 + j] = (_Float16)(b[j] * s); }
    return r;
}

#define MFMA_F16(a, b, c)  __builtin_amdgcn_mfma_f32_16x16x32_f16(a, b, c, 0, 0, 0)

// lgkm-only barrier: DS traffic drained (cross-wave h exchange); vmem gathers
// stay in flight across the barrier.
#define BAR_LGKM() do { \
    asm volatile("s_waitcnt lgkmcnt(0)" ::: "memory"); \
    __builtin_amdgcn_s_barrier(); \
} while (0)

// ============================================================================
// Precompute (folded 3-gate): gi table layout _Float16[v][128][4] = {r',z',n',0}
// r' = -log2e*(emb@wr + bir + bhr), z' likewise, n' = 2log2e*(emb@wn + bin).
// ============================================================================
__global__ __launch_bounds__(512, 2) void gi_precompute(
    const float* __restrict__ emb, const float* __restrict__ w_ih,
    const float* __restrict__ b_ih, const float* __restrict__ b_hh,
    char* __restrict__ gw) {
    __shared__ __align__(16) char xs[8192];  // [32][128] f16 swizzled
    const int tid = threadIdx.x;
    const int wv = tid >> 6;
    const int ln = tid & 63;
    const int fn = ln & 15;
    const int kg = ln >> 4;
    const int v0 = blockIdx.x * 32;
    const int gc = wv * 16 + fn;
    const int srow = tid >> 4;
    const int c8 = (tid & 15) << 3;

    {
        int v = v0 + srow; if (v >= Vv) v = Vv - 1;
        half8 hx = load_h8(emb + (size_t)v * Ee + c8);
        int off = (srow * 256 + c8 * 2) ^ ((srow & 7) << 4);
        *(half8*)(xs + off) = hx;
    }
    half8 wr[4], wz[4], wn[4];
#pragma unroll
    for (int kt = 0; kt < 4; ++kt) {
        int k0 = kt * 32 + kg * 8;
        wr[kt] = load_h8(w_ih + (size_t)gc * Ee + k0);
        wz[kt] = load_h8(w_ih + (size_t)(128 + gc) * Ee + k0);
        wn[kt] = load_h8(w_ih + (size_t)(256 + gc) * Ee + k0);
    }
    const float bcr = b_ih[gc] + b_hh[gc];
    const float bcz = b_ih[128 + gc] + b_hh[128 + gc];
    const float bcn = b_ih[256 + gc];
    __syncthreads();

    f32x4 ar[2], az[2], an[2];
#pragma unroll
    for (int mt = 0; mt < 2; ++mt) {
        ar[mt] = (f32x4){0.f, 0.f, 0.f, 0.f};
        az[mt] = (f32x4){0.f, 0.f, 0.f, 0.f};
        an[mt] = (f32x4){0.f, 0.f, 0.f, 0.f};
    }
#pragma unroll
    for (int kt = 0; kt < 4; ++kt)
#pragma unroll
        for (int mt = 0; mt < 2; ++mt) {
            int r = mt * 16 + fn;
            int off = (r * 256 + (kt * 32 + kg * 8) * 2) ^ ((r & 7) << 4);
            half8 ha = *(const half8*)(xs + off);
            ar[mt] = MFMA_F16(ha, wr[kt], ar[mt]);
            az[mt] = MFMA_F16(ha, wz[kt], az[mt]);
            an[mt] = MFMA_F16(ha, wn[kt], an[mt]);
        }
#pragma unroll
    for (int mt = 0; mt < 2; ++mt)
#pragma unroll
        for (int i = 0; i < 4; ++i) {
            int v = v0 + mt * 16 + kg * 4 + i;
            if (v < Vv) {
                half4 g;
                g[0] = (_Float16)((ar[mt][i] + bcr) * (-L2E));
                g[1] = (_Float16)((az[mt][i] + bcz) * (-L2E));
                g[2] = (_Float16)((an[mt][i] + bcn) * (2.f * L2E));
                g[3] = (_Float16)0.f;
                *(half4*)(gw + (size_t)v * 1024 + gc * 8) = g;
            }
        }
}

// ============================================================================
// Main (R13 structure, micro-opt): 16 rows/block, 8 waves, wave owns one
// 16-col tile; VGPR capped at 64 by launch_bounds(512,4) -> 2 blocks/CU
// co-resident (proven R13: occ 37%, 107us). 2-step unrolled loop with static
// buffer addressing; last 2 steps peeled (removes t2 clamp from hot loop;
// unclamped t2 at k=63 would read H0 bytes as token offsets -> OOB gather).
// LDS (21312 B): tokb [16][64] int(byte-offs) 0..4096 | H0 4096 | H1 8192 |
//                ost [16][128] f32 12288..20480 | lg 20480..21248 |
//                tstar 21248..21312
// ============================================================================
#define SM_BYTES 21312

__global__ __launch_bounds__(512, 4) void gru_slim_kernel(
    const int* __restrict__ utt, const char* __restrict__ gwc,
    const float* __restrict__ w_hh, const float* __restrict__ b_hh,
    const float* __restrict__ w_out, const float* __restrict__ b_out,
    float* __restrict__ out) {
    __shared__ __align__(16) char smem[SM_BYTES];
    int* tokb = (int*)smem;
    float* ost = (float*)(smem + 12288);
    float* lg = (float*)(smem + 20480);
    int* tstar = (int*)(smem + 21248);

    const int tid = threadIdx.x;
    const int wv = tid >> 6;      // 0..7
    const int ln = tid & 63;
    const int fn = ln & 15;
    const int kg = ln >> 4;
    const int row0 = blockIdx.x * 16;
    const int gc = wv * 16 + fn;
    const int gc8 = gc * 8;

    // ---- prologue ----
    if (tid < 16) tstar[tid] = Tt - 1;
    *(float2*)(smem + 4096 + tid * 8) = (float2){0.f, 0.f};  // H0 = h(-1) = 0
    __syncthreads();
    {
        // 16 rows * 64 tokens = 1024 ints -> int2 per thread (512 thr)
        int2 tv = ((const int2*)(utt + (size_t)row0 * Tt))[tid];
        int2 sv = {tv.x << 10, tv.y << 10};  // byte offsets into gi table
        ((int2*)tokb)[tid] = sv;
        int row = tid >> 5;
        int tq = (tid & 31) << 1;
        if (tv.x == 0) atomicMin(&tstar[row], tq);
        if (tv.y == 0) atomicMin(&tstar[row], tq + 1);
    }
    half8 whr[4], whz[4], whn[4];
#pragma unroll
    for (int kt = 0; kt < 4; ++kt) {
        int k0 = kt * 32 + kg * 8;
        whr[kt] = load_h8s(w_hh + (size_t)gc * Ee + k0, -L2E);
        whz[kt] = load_h8s(w_hh + (size_t)(128 + gc) * Ee + k0, -L2E);
        whn[kt] = load_h8s(w_hh + (size_t)(256 + gc) * Ee + k0, 2.f * L2E);
    }
    const float bhn2 = b_hh[256 + gc] * (2.f * L2E);
    __syncthreads();   // tokb + tstar ready

    int offk[4], wof[4], ts[4];
#pragma unroll
    for (int kt = 0; kt < 4; ++kt)
        offk[kt] = (fn * 256 + (kt * 32 + kg * 8) * 2) ^ ((fn & 7) << 4);
#pragma unroll
    for (int i = 0; i < 4; ++i) {
        int row = kg * 4 + i;
        wof[i] = (row * 256 + gc * 2) ^ ((row & 7) << 4);
        ts[i] = tstar[row];
    }
    const int* tokrow = tokb + kg * 256;  // tokrow[i*64 + t]

    // gi(0) into g (single buffer)
    half4 g[4];
#pragma unroll
    for (int i = 0; i < 4; ++i)
        g[i] = *(const half4*)(gwc + tokrow[i * 64] + gc8);

    f32x4 h = (f32x4){0.f, 0.f, 0.f, 0.f};

    // one step: read h(K-1) from RD, extract gi(K) from g, gather gi(T2)->g,
    // MFMA, gates, write h(K) to WR (if WRITE), barrier by caller.
#define STEP(K, T2, RD, WR, WRITE) do {                                       \
        half8 f0 = *(const half8*)((RD) + offk[0]);                           \
        half8 f1 = *(const half8*)((RD) + offk[1]);                           \
        half8 f2 = *(const half8*)((RD) + offk[2]);                           \
        half8 f3 = *(const half8*)((RD) + offk[3]);                           \
        f32x4 ar, az, an;                                                     \
        half4 pnh;                                                            \
        _Pragma("unroll")                                                     \
        for (int i = 0; i < 4; ++i) {                                         \
            ar[i] = (float)g[i][0];                                           \
            az[i] = (float)g[i][1];                                           \
            an[i] = bhn2;                                                     \
            pnh[i] = g[i][2];                                                 \
        }                                                                     \
        g[0] = *(const half4*)(gwc + tokrow[(T2)] + gc8);                     \
        g[1] = *(const half4*)(gwc + tokrow[64 + (T2)] + gc8);                \
        g[2] = *(const half4*)(gwc + tokrow[128 + (T2)] + gc8);               \
        g[3] = *(const half4*)(gwc + tokrow[192 + (T2)] + gc8);               \
        __builtin_amdgcn_s_setprio(1);                                        \
        ar = MFMA_F16(f0, whr[0], ar); az = MFMA_F16(f0, whz[0], az);         \
        an = MFMA_F16(f0, whn[0], an);                                        \
        ar = MFMA_F16(f1, whr[1], ar); az = MFMA_F16(f1, whz[1], az);         \
        an = MFMA_F16(f1, whn[1], an);                                        \
        ar = MFMA_F16(f2, whr[2], ar); az = MFMA_F16(f2, whz[2], az);         \
        an = MFMA_F16(f2, whn[2], an);                                        \
        ar = MFMA_F16(f3, whr[3], ar); az = MFMA_F16(f3, whz[3], az);         \
        an = MFMA_F16(f3, whn[3], an);                                        \
        __builtin_amdgcn_s_setprio(0);                                        \
        _Pragma("unroll")                                                     \
        for (int i = 0; i < 4; ++i) {                                         \
            float ea = fast_exp2(ar[i]);                                      \
            float eb = fast_exp2(az[i]);                                      \
            float da = 1.f + ea, db = 1.f + eb;                               \
            float R = fast_rcp(da * db);                                      \
            float rr = db * R, zz = da * R;                                   \
            float pnp = (float)pnh[i] + rr * an[i];                           \
            float ec = fast_exp2(pnp);                                        \
            float nn = 1.f - 2.f * fast_rcp(ec + 1.f);                        \
            float hv = nn + zz * (h[i] - nn);                                 \
            h[i] = hv;                                                        \
            if ((K) == ts[i]) ost[(kg * 4 + i) * Ee + gc] = hv;               \
            if (WRITE) *(_Float16*)((WR) + wof[i]) = (_Float16)hv;            \
        }                                                                     \
    } while (0)

    char* const H0 = smem + 4096;
    char* const H1 = smem + 8192;

#pragma unroll 1
    for (int k = 0; k < Tt - 2; k += 2) {
        STEP(k, k + 1, H0, H1, true);
        BAR_LGKM();  // h(k) + ost writes visible; gi gathers stay in flight
        STEP(k + 1, k + 2, H1, H0, true);
        BAR_LGKM();
    }
    // peeled tail: k=62 (gathers t2=63), k=63 (no write, gather redundant t2=63)
    STEP(Tt - 2, Tt - 1, H0, H1, true);
    BAR_LGKM();
    STEP(Tt - 1, Tt - 1, H1, H0, false);
#undef STEP

    // ---- epilogue: logits + softmax from ost ----
    __syncthreads();
    if (tid < 16 * Aa) {
        int r = tid / Aa, a = tid % Aa;
        const float* wo = w_out + a * Ee;
        const float* os = ost + r * Ee;
        float s = b_out[a];
#pragma unroll
        for (int j = 0; j < Ee; j += 4) {
            f32x4 ov = *(const f32x4*)(os + j);
            f32x4 w4 = *(const f32x4*)(wo + j);
            s += ov[0] * w4[0] + ov[1] * w4[1] + ov[2] * w4[2] + ov[3] * w4[3];
        }
        lg[r * 12 + a] = s;
    }
    __syncthreads();
    if (tid < 16) {
        float v[Aa];
        float mx = -1e30f;
#pragma unroll
        for (int a = 0; a < Aa; ++a) {
            v[a] = lg[tid * 12 + a];
            mx = fmaxf(mx, v[a]);
        }
        float sum = 0.f;
#pragma unroll
        for (int a = 0; a < Aa; ++a) {
            v[a] = __expf(v[a] - mx);
            sum += v[a];
        }
        float inv = fast_rcp(sum);
#pragma unroll
        for (int a = 0; a < Aa; ++a) out[(size_t)(row0 + tid) * Aa + a] = v[a] * inv;
    }
}

// ============================================================================
// Fallback (R5 kernel) if ws can't hold the gi table.
// ============================================================================
#define FSM_BYTES 21312
__global__ __launch_bounds__(512, 2) void gru_fallback_kernel(
    const int* __restrict__ utt, const float* __restrict__ emb,
    const float* __restrict__ w_ih, const float* __restrict__ w_hh,
    const float* __restrict__ b_ih, const float* __restrict__ b_hh,
    const float* __restrict__ w_out, const float* __restrict__ b_out,
    float* __restrict__ out) {
    __shared__ __align__(16) char smem[FSM_BYTES];
    int* tokb = (int*)smem;
    float* lg = (float*)(smem + 20480);
    int* tstar = (int*)(smem + 21248);
    float* outst = (float*)(smem + 4096);

    const int tid = threadIdx.x;
    const int wv = tid >> 6;
    const int ln = tid & 63;
    const int fn = ln & 15;
    const int kg = ln >> 4;
    const int row0 = blockIdx.x * 16;
    const int gc = wv * 16 + fn;
    const int srow = tid >> 5;
    const int c4 = (tid & 31) << 2;

    if (tid < 16) tstar[tid] = Tt - 1;
    *(float2*)(smem + 12288 + tid * 8) = (float2){0.f, 0.f};
    __syncthreads();
    {
        int2 tv = ((const int2*)(utt + (size_t)row0 * Tt))[tid];
        ((int2*)tokb)[tid] = tv;
        int row = tid >> 5;
        int tq = (tid & 31) << 1;
        if (tv.x == 0) atomicMin(&tstar[row], tq);
        if (tv.y == 0) atomicMin(&tstar[row], tq + 1);
    }
    half8 wir[4], wiz[4], win[4], whr[4], whz[4], whn[4];
#pragma unroll
    for (int kt = 0; kt < 4; ++kt) {
        int k0 = kt * 32 + kg * 8;
        wir[kt] = load_h8(w_ih + (size_t)gc * Ee + k0);
        wiz[kt] = load_h8(w_ih + (size_t)(128 + gc) * Ee + k0);
        win[kt] = load_h8(w_ih + (size_t)(256 + gc) * Ee + k0);
        whr[kt] = load_h8(w_hh + (size_t)gc * Ee + k0);
        whz[kt] = load_h8(w_hh + (size_t)(128 + gc) * Ee + k0);
        whn[kt] = load_h8(w_hh + (size_t)(256 + gc) * Ee + k0);
    }
    const float bcr = b_ih[gc] + b_hh[gc];
    const float bcz = b_ih[128 + gc] + b_hh[128 + gc];
    const float bin = b_ih[256 + gc];
    const float bhn = b_hh[256 + gc];
    __syncthreads();
    int ts[4];
#pragma unroll
    for (int i = 0; i < 4; ++i) ts[i] = tstar[kg * 4 + i];
    {
        int tok = tokb[srow * Tt];
        f32x4 a = *(const f32x4*)(emb + (size_t)tok * Ee + c4);
        half4 hx;
#pragma unroll
        for (int j = 0; j < 4; ++j) hx[j] = (_Float16)a[j];
        int off = (srow * 256 + c4 * 2) ^ ((srow & 7) << 4);
        *(half4*)(smem + 4096 + off) = hx;
    }
    __syncthreads();
    f32x4 hreg = (f32x4){0.f, 0.f, 0.f, 0.f};
    f32x4 oreg = (f32x4){0.f, 0.f, 0.f, 0.f};
    int cur = 0;
#pragma unroll 1
    for (int t = 0; t < Tt; ++t) {
        f32x4 pa;
        if (t < Tt - 1) {
            int tok = tokb[srow * Tt + t + 1];
            pa = *(const f32x4*)(emb + (size_t)tok * Ee + c4);
        }
        const char* xb = smem + 4096 + cur * 4096;
        const char* hb = smem + 12288 + cur * 4096;
        f32x4 ar = (f32x4){0.f, 0.f, 0.f, 0.f};
        f32x4 az = (f32x4){0.f, 0.f, 0.f, 0.f};
        f32x4 ain = (f32x4){0.f, 0.f, 0.f, 0.f};
        f32x4 ahn = (f32x4){0.f, 0.f, 0.f, 0.f};
        __builtin_amdgcn_s_setprio(1);
#pragma unroll
        for (int kt = 0; kt < 4; ++kt) {
            int off = (fn * 256 + (kt * 32 + kg * 8) * 2) ^ ((fn & 7) << 4);
            half8 xa = *(const half8*)(xb + off);
            half8 ha = *(const half8*)(hb + off);
            ar = MFMA_F16(xa, wir[kt], ar);
            ar = MFMA_F16(ha, whr[kt], ar);
            az = MFMA_F16(xa, wiz[kt], az);
            az = MFMA_F16(ha, whz[kt], az);
            ain = MFMA_F16(xa, win[kt], ain);
            ahn = MFMA_F16(ha, whn[kt], ahn);
        }
        __builtin_amdgcn_s_setprio(0);
        char* hn = smem + 12288 + (cur ^ 1) * 4096;
#pragma unroll
        for (int i = 0; i < 4; ++i) {
            float pr = ar[i] + bcr;
            float pz = az[i] + bcz;
            float rr = fast_rcp(1.f + __expf(-pr));
            float zz = fast_rcp(1.f + __expf(-pz));
            float pn = ain[i] + bin + rr * (ahn[i] + bhn);
            float e2 = __expf(2.f * pn);
            float nn = 1.f - 2.f * fast_rcp(e2 + 1.f);
            float h = (1.f - zz) * nn + zz * hreg[i];
            hreg[i] = h;
            if (t == ts[i]) oreg[i] = h;
            if (t < Tt - 1) {
                int row = kg * 4 + i;
                int off = (row * 256 + gc * 2) ^ ((row & 7) << 4);
                *(_Float16*)(hn + off) = (_Float16)h;
            }
        }
        if (t < Tt - 1) {
            half4 hx;
#pragma unroll
            for (int j = 0; j < 4; ++j) hx[j] = (_Float16)pa[j];
            int off = (srow * 256 + c4 * 2) ^ ((srow & 7) << 4);
            *(half4*)(smem + 4096 + (cur ^ 1) * 4096 + off) = hx;
        }
        __syncthreads();
        cur ^= 1;
    }
#pragma unroll
    for (int i = 0; i < 4; ++i) outst[(kg * 4 + i) * Ee + gc] = oreg[i];
    __syncthreads();
    if (tid < 16 * Aa) {
        int r = tid / Aa, a = tid % Aa;
        const float* wo = w_out + a * Ee;
        const float* os = outst + r * Ee;
        float s = b_out[a];
#pragma unroll
        for (int j = 0; j < Ee; j += 4) {
            f32x4 o = *(const f32x4*)(os + j);
            f32x4 w4 = *(const f32x4*)(wo + j);
            s += o[0] * w4[0] + o[1] * w4[1] + o[2] * w4[2] + o[3] * w4[3];
        }
        lg[r * 12 + a] = s;
    }
    __syncthreads();
    if (tid < 16) {
        float v[Aa];
        float mx = -1e30f;
#pragma unroll
        for (int a = 0; a < Aa; ++a) {
            v[a] = lg[tid * 12 + a];
            mx = fmaxf(mx, v[a]);
        }
        float sum = 0.f;
#pragma unroll
        for (int a = 0; a < Aa; ++a) {
            v[a] = __expf(v[a] - mx);
            sum += v[a];
        }
        float inv = fast_rcp(sum);
#pragma unroll
        for (int a = 0; a < Aa; ++a) out[(size_t)(row0 + tid) * Aa + a] = v[a] * inv;
    }
}

extern "C" void kernel_launch(void* const* d_in, const int* in_sizes, int n_in,
                              void* d_out, int out_size, void* d_ws, size_t ws_size,
                              hipStream_t stream) {
    (void)in_sizes; (void)n_in; (void)out_size;
    const int* utt = (const int*)d_in[0];
    const float* emb = (const float*)d_in[2];
    const float* wih = (const float*)d_in[3];
    const float* whh = (const float*)d_in[4];
    const float* bih = (const float*)d_in[5];
    const float* bhh = (const float*)d_in[6];
    const float* wout = (const float*)d_in[7];
    const float* bout = (const float*)d_in[8];
    const size_t need = (size_t)Vv * 1024;  // 32.77 MB
    if (ws_size >= need) {
        char* gw = (char*)d_ws;
        gi_precompute<<<dim3((Vv + 31) / 32), 512, 0, stream>>>(emb, wih, bih, bhh, gw);
        gru_slim_kernel<<<512, 512, 0, stream>>>(utt, gw, whh, bhh, wout, bout, (float*)d_out);
    } else {
        gru_fallback_kernel<<<512, 512, 0, stream>>>(utt, emb, wih, whh, bih, bhh, wout, bout,
                                                     (float*)d_out);
    }
}